// Round 9
// baseline (693.212 us; speedup 1.0000x reference)
//
#include <hip/hip_runtime.h>
#include <hip/hip_fp16.h>
#include <cstddef>

typedef _Float16 f16;
typedef f16 f16x8 __attribute__((ext_vector_type(8)));
typedef float f32x4 __attribute__((ext_vector_type(4)));

__device__ __forceinline__ unsigned f2mono(float f){
  unsigned u = __float_as_uint(f);
  return (u & 0x80000000u) ? ~u : (u | 0x80000000u);
}
__device__ __forceinline__ float mono2f(unsigned u){
  return (u & 0x80000000u) ? __uint_as_float(u & 0x7fffffffu) : __uint_as_float(~u);
}

// ---------------- weight cast f32 -> f16, 8 x 128x128 ---------------------------
struct WPtrs { const float* w[8]; };
__global__ void k_wcast(WPtrs p, f16* __restrict__ Wh){
  int wi = blockIdx.y;
  const float* W = p.w[wi];
  f16* dst = Wh + (size_t)wi * 16384;
  int i = (blockIdx.x*256 + threadIdx.x) * 8;          // grid.x=8 -> 16384 elems
  float4 v0 = *(const float4*)(W + i), v1 = *(const float4*)(W + i + 4);
  f16x8 h = {(f16)v0.x,(f16)v0.y,(f16)v0.z,(f16)v0.w,
             (f16)v1.x,(f16)v1.y,(f16)v1.z,(f16)v1.w};
  *(f16x8*)(dst + i) = h;
}
// ---------------- x cast f32 -> f16 ---------------------------------------------
__global__ void k_castx(const float* __restrict__ x, __half* __restrict__ xh, int total){
  int i = (blockIdx.x*256 + threadIdx.x) * 8;
  if (i >= total) return;
  float4 v0 = *(const float4*)(x + i), v1 = *(const float4*)(x + i + 4);
  f16x8 h = {(f16)v0.x,(f16)v0.y,(f16)v0.z,(f16)v0.w,
             (f16)v1.x,(f16)v1.y,(f16)v1.z,(f16)v1.w};
  *(f16x8*)((f16*)xh + i) = h;
}

// ---------------- MFMA f16 GEMM, f16 in, f32/f16 out ----------------------------
// out[r][j] = act(sum_k in[r][k]*W[j][k] + b[j]) (+res). 64 rows/block, 4 waves.
// LDS stride 130 f16 (65 dw = 1 bank mod 32) -> ~2-way conflicts (free, m136).
template<int ACT>   // 0 none, 1 relu
__global__ __launch_bounds__(256) void k_gemm_f16(
    const __half* __restrict__ in, const f16* __restrict__ Wm,
    const float* __restrict__ bias, const float* __restrict__ res,
    float* __restrict__ outF, __half* __restrict__ outH, int n)
{
  constexpr int LDW = 130;
  __shared__ f16 Wl[128*LDW];
  __shared__ f16 Al[64*LDW];
  const int tid = threadIdx.x;
  const int r0 = blockIdx.x * 64;
#pragma unroll
  for (int i = 0; i < 8; i++){
    int u = tid + 256*i; int row = u >> 4, c8 = (u & 15) * 8;
    *(f16x8*)&Wl[row*LDW + c8] = *(const f16x8*)(Wm + row*128 + c8);
  }
#pragma unroll
  for (int i = 0; i < 4; i++){
    int u = tid + 256*i; int row = u >> 4, c8 = (u & 15) * 8;
    int gr = r0 + row;
    f16x8 v = {};
    if (gr < n) v = *(const f16x8*)((const f16*)in + (size_t)gr*128 + c8);
    *(f16x8*)&Al[row*LDW + c8] = v;
  }
  __syncthreads();
  const int wv = tid >> 6, lane = tid & 63;
  const int l15 = lane & 15, quad = lane >> 4;
  f32x4 acc[8] = {};
  const f16* Ab = &Al[(wv*16 + l15)*LDW + quad*8];
  const f16* Bb = &Wl[l15*LDW + quad*8];
#pragma unroll
  for (int kc = 0; kc < 4; kc++){
    f16x8 a = *(const f16x8*)(Ab + kc*32);
#pragma unroll
    for (int nt = 0; nt < 8; nt++){
      f16x8 b = *(const f16x8*)(Bb + nt*16*LDW + kc*32);
      acc[nt] = __builtin_amdgcn_mfma_f32_16x16x32_f16(a, b, acc[nt], 0, 0, 0);
    }
  }
#pragma unroll
  for (int nt = 0; nt < 8; nt++){
    int col = nt*16 + l15;
    float bv = bias ? bias[col] : 0.f;
#pragma unroll
    for (int reg = 0; reg < 4; reg++){
      int gr = r0 + wv*16 + quad*4 + reg;
      if (gr >= n) continue;
      float o = acc[nt][reg] + bv;
      if (ACT == 1) o = fmaxf(o, 0.f);
      if (res) o += res[(size_t)gr*128 + col];
      if (outF) outF[(size_t)gr*128 + col] = o;
      if (outH) outH[(size_t)gr*128 + col] = __float2half(o);
    }
  }
}

// ---------------- attention logits prep (xp in fp16) ---------------------------
__global__ void k_prep8(const __half* __restrict__ xp, const float* __restrict__ As,
                        const float* __restrict__ Ad, float* __restrict__ es,
                        float* __restrict__ ed, int N){
  int t = blockIdx.x*blockDim.x + threadIdx.x;
  if (t >= N*8) return;
  int node = t >> 3, h = t & 7;
  const __half2* xr = (const __half2*)(xp + (size_t)node*128 + h*16);
  float ss = 0.f, sd = 0.f;
#pragma unroll
  for (int w = 0; w < 8; w++){
    float2 v = __half22float2(xr[w]);
    int i = h*16 + w*2;
    ss += v.x*As[i] + v.y*As[i+1];
    sd += v.x*Ad[i] + v.y*Ad[i+1];
  }
  es[t] = ss; ed[t] = sd;
}
__global__ __launch_bounds__(256) void k_prep1(const __half* __restrict__ xp,
    const float* __restrict__ As, const float* __restrict__ Ad,
    float* __restrict__ es, float* __restrict__ ed, int N){
  int gw = (blockIdx.x*256 + threadIdx.x) >> 6;
  if (gw >= N) return;
  int lane = threadIdx.x & 63;
  float2 x = __half22float2(*(const __half2*)(xp + (size_t)gw*128 + lane*2));
  float s = x.x*As[lane*2] + x.y*As[lane*2+1];
  float d = x.x*Ad[lane*2] + x.y*Ad[lane*2+1];
#pragma unroll
  for (int o = 32; o > 0; o >>= 1){ s += __shfl_down(s, o); d += __shfl_down(d, o); }
  if (lane == 0){ es[gw] = s; ed[gw] = d; }
}

// ---------------- CSR build -----------------------------------------------------
__global__ void k_deg(const int* __restrict__ ei, int* __restrict__ deg, int E, int N){
  int t = blockIdx.x*blockDim.x + threadIdx.x;
  if (t >= E + N) return;
  int d = (t < E) ? ei[E + t] : (t - E);
  atomicAdd(&deg[d], 1);
}
__global__ void k_scan1(const int* __restrict__ deg, int* __restrict__ bsum, int N){
  __shared__ int sd[256];
  int i = blockIdx.x*256 + threadIdx.x;
  sd[threadIdx.x] = (i < N) ? deg[i] : 0;
  __syncthreads();
  for (int s = 128; s > 0; s >>= 1){
    if (threadIdx.x < s) sd[threadIdx.x] += sd[threadIdx.x + s];
    __syncthreads();
  }
  if (threadIdx.x == 0) bsum[blockIdx.x] = sd[0];
}
// parallel exclusive scan over block sums (nb <= 256)
__global__ void k_scan2(const int* __restrict__ bsum, int* __restrict__ boff, int nb){
  __shared__ int sd[256];
  int t = threadIdx.x;
  int v = (t < nb) ? bsum[t] : 0;
  sd[t] = v;
  __syncthreads();
  for (int s = 1; s < 256; s <<= 1){
    int u = (t >= s) ? sd[t - s] : 0;
    __syncthreads();
    sd[t] += u;
    __syncthreads();
  }
  if (t < nb) boff[t] = sd[t] - v;
}
__global__ void k_scan3(const int* __restrict__ deg, const int* __restrict__ boff,
                        int* __restrict__ rowptr, int N){
  __shared__ int sd[256];
  int tid = threadIdx.x;
  int i = blockIdx.x*256 + tid;
  sd[tid] = (i < N) ? deg[i] : 0;
  __syncthreads();
  for (int s = 1; s < 256; s <<= 1){
    int t = (tid >= s) ? sd[tid - s] : 0;
    __syncthreads();
    sd[tid] += t;
    __syncthreads();
  }
  if (i < N) rowptr[i+1] = boff[blockIdx.x] + sd[tid];
  if (i == 0) rowptr[0] = 0;
}
__global__ void k_fill(const int* __restrict__ ei, const int* __restrict__ rowptr,
                       int* __restrict__ fil, int* __restrict__ csr, int E, int N){
  int t = blockIdx.x*blockDim.x + threadIdx.x;
  if (t >= E + N) return;
  int s, d;
  if (t < E){ s = ei[t]; d = ei[E + t]; } else { s = d = t - E; }
  int pos = rowptr[d] + atomicAdd(&fil[d], 1);
  csr[pos] = s;
}

// ---------------- GAT aggregate: direct exp, writes f32 + f16 shadow ------------
template<int H, int D>
__global__ __launch_bounds__(256) void k_aggregate(
    const __half* __restrict__ xp, const float* __restrict__ es, const float* __restrict__ ed,
    const int* __restrict__ rowptr, const int* __restrict__ csr,
    const float* __restrict__ bg, const float* res,
    float* out, __half* __restrict__ outH, int N)
{
  int gw = (blockIdx.x*256 + threadIdx.x) >> 6;
  if (gw >= N) return;
  int lane = threadIdx.x & 63;
  int j0 = lane*2;
  int h0 = j0 / D;
  int beg = rowptr[gw], end = rowptr[gw+1];
  float edv = ed[gw*H + h0];
  float den = 0.f, a0 = 0.f, a1 = 0.f;
  int t = beg;
  for (; t + 4 <= end; t += 4){
    int s0 = csr[t], s1 = csr[t+1], s2 = csr[t+2], s3 = csr[t+3];
    float e0 = es[s0*H + h0] + edv; e0 = e0 > 0.f ? e0 : 0.2f*e0;
    float e1 = es[s1*H + h0] + edv; e1 = e1 > 0.f ? e1 : 0.2f*e1;
    float e2 = es[s2*H + h0] + edv; e2 = e2 > 0.f ? e2 : 0.2f*e2;
    float e3 = es[s3*H + h0] + edv; e3 = e3 > 0.f ? e3 : 0.2f*e3;
    __half2 q0 = *(const __half2*)(xp + (size_t)s0*128 + j0);
    __half2 q1 = *(const __half2*)(xp + (size_t)s1*128 + j0);
    __half2 q2 = *(const __half2*)(xp + (size_t)s2*128 + j0);
    __half2 q3 = *(const __half2*)(xp + (size_t)s3*128 + j0);
    float w0 = __expf(e0), w1 = __expf(e1), w2 = __expf(e2), w3 = __expf(e3);
    float2 f0 = __half22float2(q0), f1 = __half22float2(q1);
    float2 f2 = __half22float2(q2), f3 = __half22float2(q3);
    den += (w0 + w1) + (w2 + w3);
    a0  += w0*f0.x + w1*f1.x + w2*f2.x + w3*f3.x;
    a1  += w0*f0.y + w1*f1.y + w2*f2.y + w3*f3.y;
  }
  for (; t < end; t++){
    int s = csr[t];
    float e = es[s*H + h0] + edv;
    e = e > 0.f ? e : 0.2f*e;
    float w = __expf(e);
    float2 f = __half22float2(*(const __half2*)(xp + (size_t)s*128 + j0));
    den += w;
    a0  += w*f.x;
    a1  += w*f.y;
  }
  float inv = 1.f / den;
  float o0 = a0*inv + bg[j0];
  float o1 = a1*inv + bg[j0+1];
  o0 = o0 > 0.f ? o0 : __expf(o0) - 1.f;
  o1 = o1 > 0.f ? o1 : __expf(o1) - 1.f;
  if (res){ o0 += res[(size_t)gw*128 + j0]; o1 += res[(size_t)gw*128 + j0 + 1]; }
  *(float2*)(out + (size_t)gw*128 + j0) = make_float2(o0, o1);
  *(__half2*)(outH + (size_t)gw*128 + j0) = __floats2half2_rn(o0, o1);
}

// ---------------- pooling --------------------------------------------------------
__global__ __launch_bounds__(128) void k_pool(const float* __restrict__ enh,
    const int* __restrict__ batch, float* __restrict__ Ps, float* __restrict__ Pss,
    unsigned* __restrict__ Pmx, float* __restrict__ Pcnt, int N)
{
  int tid = threadIdx.x;
  int n0 = blockIdx.x * 128;
  if (n0 >= N) return;
  int n1 = min(n0 + 128, N);
  int cur = batch[n0];
  float sum = 0.f, ssq = 0.f, mx = -1e30f, cnt = 0.f;
  auto flush = [&](int b){
    atomicAdd(&Ps[b*128 + tid], sum);
    atomicAdd(&Pss[b*128 + tid], ssq);
    atomicMax(&Pmx[b*128 + tid], f2mono(mx));
    if (tid == 0) atomicAdd(&Pcnt[b], cnt);
  };
  for (int i = n0; i < n1; i++){
    int b = batch[i];
    if (b != cur){ flush(cur); cur = b; sum = 0.f; ssq = 0.f; mx = -1e30f; cnt = 0.f; }
    float v = enh[(size_t)i*128 + tid];
    sum += v; ssq += v*v; mx = fmaxf(mx, v); cnt += 1.f;
  }
  flush(cur);
}

// ---------------- fused poolfin + cls1 -------------------------------------------
__global__ void k_poolcls(const float* __restrict__ Ps, const float* __restrict__ Pss,
    const unsigned* __restrict__ Pmx, const float* __restrict__ Pcnt,
    const float* __restrict__ Wc1, const float* __restrict__ bc1, float* __restrict__ c1b)
{
  __shared__ float gs[384];
  int b = blockIdx.x, j = threadIdx.x;             // 64 x 128
  float cnt = Pcnt[b];
  float c = fmaxf(cnt, 1.f);
  float mean = Ps[b*128 + j] / c;
  float var = (Pss[b*128 + j] - c*mean*mean) / fmaxf(cnt - 1.f, 1.f);
  float sd = (cnt > 1.f) ? sqrtf(fmaxf(var, 0.f)) : 0.f;
  gs[j] = mean; gs[128 + j] = mono2f(Pmx[b*128 + j]); gs[256 + j] = sd;
  __syncthreads();
  float acc = bc1[j];
  for (int i = 0; i < 384; i++) acc += gs[i] * Wc1[j*384 + i];
  c1b[b*128 + j] = fmaxf(acc, 0.f);
}
// ---------------- fused cls2 + cls3 ----------------------------------------------
__global__ void k_cls23(const float* __restrict__ c1b, const float* __restrict__ Wc2,
    const float* __restrict__ bc2, const float* __restrict__ Wc3,
    const float* __restrict__ bc3, float* __restrict__ out)
{
  __shared__ float hs[128];
  __shared__ float h2[64];
  int b = blockIdx.x, t = threadIdx.x;             // 64 x 64
  hs[t] = c1b[b*128 + t]; hs[t + 64] = c1b[b*128 + t + 64];
  __syncthreads();
  float acc = bc2[t];
  for (int i = 0; i < 128; i++) acc += hs[i] * Wc2[t*128 + i];
  h2[t] = fmaxf(acc, 0.f);
  __syncthreads();
  if (t < 2){
    float a = bc3[t];
    for (int i = 0; i < 64; i++) a += h2[i] * Wc3[t*64 + i];
    out[b*2 + t] = a;
  }
}

// ---------------- launch ---------------------------------------------------------
extern "C" void kernel_launch(void* const* d_in, const int* in_sizes, int n_in,
                              void* d_out, int out_size, void* d_ws, size_t ws_size,
                              hipStream_t stream)
{
  const float* x    = (const float*)d_in[0];
  const int*  ei    = (const int*)d_in[1];
  const int*  batch = (const int*)d_in[2];
  const float* Wi1  = (const float*)d_in[3];  const float* bi1 = (const float*)d_in[4];
  const float* Wi2  = (const float*)d_in[5];  const float* bi2 = (const float*)d_in[6];
  const float* Wg[4]= {(const float*)d_in[7],(const float*)d_in[11],(const float*)d_in[15],(const float*)d_in[19]};
  const float* As[4]= {(const float*)d_in[8],(const float*)d_in[12],(const float*)d_in[16],(const float*)d_in[20]};
  const float* Ad[4]= {(const float*)d_in[9],(const float*)d_in[13],(const float*)d_in[17],(const float*)d_in[21]};
  const float* bg[4]= {(const float*)d_in[10],(const float*)d_in[14],(const float*)d_in[18],(const float*)d_in[22]};
  const float* We1  = (const float*)d_in[23]; const float* be1 = (const float*)d_in[24];
  const float* We2  = (const float*)d_in[25]; const float* be2 = (const float*)d_in[26];
  const float* Wc1  = (const float*)d_in[27]; const float* bc1 = (const float*)d_in[28];
  const float* Wc2  = (const float*)d_in[29]; const float* bc2 = (const float*)d_in[30];
  const float* Wc3  = (const float*)d_in[31]; const float* bc3 = (const float*)d_in[32];
  float* outp = (float*)d_out;

  const int N = in_sizes[2];
  const int E = in_sizes[1] / 2;
  const int Etot = E + N;

  float* base = (float*)d_ws;
  size_t off = 0;
  auto alloc = [&](size_t elems) -> float* {
    float* p = base + off;
    off += (elems + 3) & ~(size_t)3;
    return p;
  };
  float* A    = alloc((size_t)N * 128);          // f32 residual stream / enh
  __half* Bh  = (__half*)alloc((size_t)N * 64);  // f16 gemm scratch
  __half* Xh  = (__half*)alloc((size_t)N * 64);  // f16 xp (also cast-of-x)
  __half* Ah  = (__half*)alloc((size_t)N * 64);  // f16 shadow of A
  f16* Wh     = (f16*)alloc(8 * 8192);           // 8 x 128x128 f16 weights
  float* es   = alloc((size_t)N * 8);
  float* ed   = alloc((size_t)N * 8);
  float* Ps   = alloc(64 * 128);                 // Ps..fil contiguous -> ONE memset
  float* Pss  = alloc(64 * 128);
  unsigned* Pmx = (unsigned*)alloc(64 * 128);
  float* Pcnt = alloc(64);
  int* deg    = (int*)alloc(N);
  int* fil    = (int*)alloc(N);
  int* rowptr = (int*)alloc(N + 1);
  int* bsum   = (int*)alloc(512);
  int* boff   = (int*)alloc(512);
  int* csr    = (int*)alloc(Etot);
  float* c1b  = alloc(64 * 128);
  (void)ws_size; (void)n_in; (void)out_size;

  (void)hipMemsetAsync(Ps, 0, sizeof(float) * (3*8192 + 64) + sizeof(int) * 2 * (size_t)N, stream);

  WPtrs wp;
  wp.w[0]=Wi1; wp.w[1]=Wi2; wp.w[2]=Wg[0]; wp.w[3]=Wg[1]; wp.w[4]=Wg[2]; wp.w[5]=Wg[3]; wp.w[6]=We1; wp.w[7]=We2;
  k_wcast<<<dim3(8, 8), 256, 0, stream>>>(wp, Wh);
  k_castx<<<(N*128/8 + 255) / 256, 256, 0, stream>>>(x, Xh, N*128);

  const int gtiles = (N + 63) / 64;
  k_gemm_f16<1><<<gtiles, 256, 0, stream>>>(Xh, Wh + 0*16384, bi1, nullptr, nullptr, Bh, N);
  k_gemm_f16<0><<<gtiles, 256, 0, stream>>>(Bh, Wh + 1*16384, bi2, nullptr, A, Ah, N);

  const int nb = (N + 255) / 256;
  k_deg  <<<(Etot + 255) / 256, 256, 0, stream>>>(ei, deg, E, N);
  k_scan1<<<nb, 256, 0, stream>>>(deg, bsum, N);
  k_scan2<<<1, 256, 0, stream>>>(bsum, boff, nb);
  k_scan3<<<nb, 256, 0, stream>>>(deg, boff, rowptr, N);
  k_fill <<<(Etot + 255) / 256, 256, 0, stream>>>(ei, rowptr, fil, csr, E, N);

  for (int l = 0; l < 4; l++){
    k_gemm_f16<0><<<gtiles, 256, 0, stream>>>(Ah, Wh + (size_t)(2+l)*16384, nullptr, nullptr, nullptr, Xh, N);
    if (l < 3){
      k_prep8<<<(N*8 + 255) / 256, 256, 0, stream>>>(Xh, As[l], Ad[l], es, ed, N);
      k_aggregate<8,16><<<(N + 3) / 4, 256, 0, stream>>>(Xh, es, ed, rowptr, csr, bg[l],
                                                         l > 0 ? A : nullptr, A, Ah, N);
    } else {
      k_prep1<<<(N + 3) / 4, 256, 0, stream>>>(Xh, As[3], Ad[3], es, ed, N);
      k_aggregate<1,128><<<(N + 3) / 4, 256, 0, stream>>>(Xh, es, ed, rowptr, csr, bg[3], A, A, Ah, N);
    }
  }

  // enh = A + (relu(A@We1^T+be1)@We2^T + be2), into A (f32)
  k_gemm_f16<1><<<gtiles, 256, 0, stream>>>(Ah, Wh + 6*16384, be1, nullptr, nullptr, Bh, N);
  k_gemm_f16<0><<<gtiles, 256, 0, stream>>>(Bh, Wh + 7*16384, be2, A, A, nullptr, N);

  k_pool   <<<(N + 127) / 128, 128, 0, stream>>>(A, batch, Ps, Pss, Pmx, Pcnt, N);
  k_poolcls<<<64, 128, 0, stream>>>(Ps, Pss, Pmx, Pcnt, Wc1, bc1, c1b);
  k_cls23  <<<64, 64, 0, stream>>>(c1b, Wc2, bc2, Wc3, bc3, outp);
}

// Round 10
// 638.427 us; speedup vs baseline: 1.0858x; 1.0858x over previous
//
#include <hip/hip_runtime.h>
#include <hip/hip_fp16.h>
#include <cstddef>

typedef _Float16 f16;
typedef f16 f16x8 __attribute__((ext_vector_type(8)));
typedef float f32x4 __attribute__((ext_vector_type(4)));

__device__ __forceinline__ unsigned f2mono(float f){
  unsigned u = __float_as_uint(f);
  return (u & 0x80000000u) ? ~u : (u | 0x80000000u);
}
__device__ __forceinline__ float mono2f(unsigned u){
  return (u & 0x80000000u) ? __uint_as_float(u & 0x7fffffffu) : __uint_as_float(~u);
}

// ---------------- weight cast f32 -> f16, 8 x 128x128 ---------------------------
struct WPtrs { const float* w[8]; };
__global__ void k_wcast(WPtrs p, f16* __restrict__ Wh){
  int wi = blockIdx.y;
  const float* W = p.w[wi];
  f16* dst = Wh + (size_t)wi * 16384;
  int i = (blockIdx.x*256 + threadIdx.x) * 8;          // grid.x=8 -> 16384 elems
  float4 v0 = *(const float4*)(W + i), v1 = *(const float4*)(W + i + 4);
  f16x8 h = {(f16)v0.x,(f16)v0.y,(f16)v0.z,(f16)v0.w,
             (f16)v1.x,(f16)v1.y,(f16)v1.z,(f16)v1.w};
  *(f16x8*)(dst + i) = h;
}
// ---------------- x cast f32 -> f16 ---------------------------------------------
__global__ void k_castx(const float* __restrict__ x, __half* __restrict__ xh, int total){
  int i = (blockIdx.x*256 + threadIdx.x) * 8;
  if (i >= total) return;
  float4 v0 = *(const float4*)(x + i), v1 = *(const float4*)(x + i + 4);
  f16x8 h = {(f16)v0.x,(f16)v0.y,(f16)v0.z,(f16)v0.w,
             (f16)v1.x,(f16)v1.y,(f16)v1.z,(f16)v1.w};
  *(f16x8*)((f16*)xh + i) = h;
}

// ---------------- MFMA f16 GEMM v4: 32 rows x 64 cols per block ------------------
// grid = 2 * ceil(n/32); blockIdx&1 = col half, blockIdx>>1 = row tile.
// LDS ~24.4 KB -> 6 blocks/CU (24 waves/CU) for latency hiding.
// out[r][j] = act(sum_k in[r][k]*W[j][k] + b[j]) (+res).
template<int ACT>   // 0 none, 1 relu
__global__ __launch_bounds__(256) void k_gemm_f16(
    const __half* __restrict__ in, const f16* __restrict__ Wm,
    const float* __restrict__ bias, const float* __restrict__ res,
    float* __restrict__ outF, __half* __restrict__ outH, int n)
{
  constexpr int LDW = 130;                // 65 dwords -> bank+1 per row: ~2-way max (free)
  __shared__ f16 Wl[64*LDW];              // 64 out-cols x 128 k
  __shared__ f16 Al[32*LDW];              // 32 rows x 128 k
  const int tid = threadIdx.x;
  const int ch = blockIdx.x & 1;
  const int r0 = (blockIdx.x >> 1) * 32;
#pragma unroll
  for (int i = 0; i < 4; i++){
    int u = tid + 256*i; int row = u >> 4, c8 = (u & 15) * 8;
    *(f16x8*)&Wl[row*LDW + c8] = *(const f16x8*)(Wm + (size_t)(ch*64 + row)*128 + c8);
  }
#pragma unroll
  for (int i = 0; i < 2; i++){
    int u = tid + 256*i; int row = u >> 4, c8 = (u & 15) * 8;
    int gr = r0 + row;
    f16x8 v = {};
    if (gr < n) v = *(const f16x8*)((const f16*)in + (size_t)gr*128 + c8);
    *(f16x8*)&Al[row*LDW + c8] = v;
  }
  __syncthreads();
  const int wv = tid >> 6, lane = tid & 63;
  const int l15 = lane & 15, quad = lane >> 4;
  const int rh = wv & 1, cq = wv >> 1;    // wave: 16 rows x 32 cols
  f32x4 acc[2] = {};
  const f16* Ab = &Al[(rh*16 + l15)*LDW + quad*8];
  const f16* Bb = &Wl[(cq*32 + l15)*LDW + quad*8];
#pragma unroll
  for (int kc = 0; kc < 4; kc++){
    f16x8 a = *(const f16x8*)(Ab + kc*32);
#pragma unroll
    for (int nt = 0; nt < 2; nt++){
      f16x8 b = *(const f16x8*)(Bb + nt*16*LDW + kc*32);
      acc[nt] = __builtin_amdgcn_mfma_f32_16x16x32_f16(a, b, acc[nt], 0, 0, 0);
    }
  }
#pragma unroll
  for (int nt = 0; nt < 2; nt++){
    int col = ch*64 + cq*32 + nt*16 + l15;
    float bv = bias ? bias[col] : 0.f;
#pragma unroll
    for (int reg = 0; reg < 4; reg++){
      int gr = r0 + rh*16 + quad*4 + reg;
      if (gr >= n) continue;
      float o = acc[nt][reg] + bv;
      if (ACT == 1) o = fmaxf(o, 0.f);
      if (res) o += res[(size_t)gr*128 + col];
      if (outF) outF[(size_t)gr*128 + col] = o;
      if (outH) outH[(size_t)gr*128 + col] = __float2half(o);
    }
  }
}

// ---------------- attention logits prep (xp in fp16) ---------------------------
__global__ void k_prep8(const __half* __restrict__ xp, const float* __restrict__ As,
                        const float* __restrict__ Ad, float* __restrict__ es,
                        float* __restrict__ ed, int N){
  int t = blockIdx.x*blockDim.x + threadIdx.x;
  if (t >= N*8) return;
  int node = t >> 3, h = t & 7;
  const __half2* xr = (const __half2*)(xp + (size_t)node*128 + h*16);
  float ss = 0.f, sd = 0.f;
#pragma unroll
  for (int w = 0; w < 8; w++){
    float2 v = __half22float2(xr[w]);
    int i = h*16 + w*2;
    ss += v.x*As[i] + v.y*As[i+1];
    sd += v.x*Ad[i] + v.y*Ad[i+1];
  }
  es[t] = ss; ed[t] = sd;
}
__global__ __launch_bounds__(256) void k_prep1(const __half* __restrict__ xp,
    const float* __restrict__ As, const float* __restrict__ Ad,
    float* __restrict__ es, float* __restrict__ ed, int N){
  int gw = (blockIdx.x*256 + threadIdx.x) >> 6;
  if (gw >= N) return;
  int lane = threadIdx.x & 63;
  float2 x = __half22float2(*(const __half2*)(xp + (size_t)gw*128 + lane*2));
  float s = x.x*As[lane*2] + x.y*As[lane*2+1];
  float d = x.x*Ad[lane*2] + x.y*Ad[lane*2+1];
#pragma unroll
  for (int o = 32; o > 0; o >>= 1){ s += __shfl_down(s, o); d += __shfl_down(d, o); }
  if (lane == 0){ es[gw] = s; ed[gw] = d; }
}

// ---------------- CSR build -----------------------------------------------------
__global__ void k_deg(const int* __restrict__ ei, int* __restrict__ deg, int E, int N){
  int t = blockIdx.x*blockDim.x + threadIdx.x;
  if (t >= E + N) return;
  int d = (t < E) ? ei[E + t] : (t - E);
  atomicAdd(&deg[d], 1);
}
__global__ void k_scan1(const int* __restrict__ deg, int* __restrict__ bsum, int N){
  __shared__ int sd[256];
  int i = blockIdx.x*256 + threadIdx.x;
  sd[threadIdx.x] = (i < N) ? deg[i] : 0;
  __syncthreads();
  for (int s = 128; s > 0; s >>= 1){
    if (threadIdx.x < s) sd[threadIdx.x] += sd[threadIdx.x + s];
    __syncthreads();
  }
  if (threadIdx.x == 0) bsum[blockIdx.x] = sd[0];
}
__global__ void k_scan2(const int* __restrict__ bsum, int* __restrict__ boff, int nb){
  __shared__ int sd[256];
  int t = threadIdx.x;
  int v = (t < nb) ? bsum[t] : 0;
  sd[t] = v;
  __syncthreads();
  for (int s = 1; s < 256; s <<= 1){
    int u = (t >= s) ? sd[t - s] : 0;
    __syncthreads();
    sd[t] += u;
    __syncthreads();
  }
  if (t < nb) boff[t] = sd[t] - v;
}
__global__ void k_scan3(const int* __restrict__ deg, const int* __restrict__ boff,
                        int* __restrict__ rowptr, int N){
  __shared__ int sd[256];
  int tid = threadIdx.x;
  int i = blockIdx.x*256 + tid;
  sd[tid] = (i < N) ? deg[i] : 0;
  __syncthreads();
  for (int s = 1; s < 256; s <<= 1){
    int t = (tid >= s) ? sd[tid - s] : 0;
    __syncthreads();
    sd[tid] += t;
    __syncthreads();
  }
  if (i < N) rowptr[i+1] = boff[blockIdx.x] + sd[tid];
  if (i == 0) rowptr[0] = 0;
}
__global__ void k_fill(const int* __restrict__ ei, const int* __restrict__ rowptr,
                       int* __restrict__ fil, int* __restrict__ csr, int E, int N){
  int t = blockIdx.x*blockDim.x + threadIdx.x;
  if (t >= E + N) return;
  int s, d;
  if (t < E){ s = ei[t]; d = ei[E + t]; } else { s = d = t - E; }
  int pos = rowptr[d] + atomicAdd(&fil[d], 1);
  csr[pos] = s;
}

// ---------------- GAT aggregate: direct exp, writes f32 + f16 shadow ------------
template<int H, int D>
__global__ __launch_bounds__(256) void k_aggregate(
    const __half* __restrict__ xp, const float* __restrict__ es, const float* __restrict__ ed,
    const int* __restrict__ rowptr, const int* __restrict__ csr,
    const float* __restrict__ bg, const float* res,
    float* out, __half* __restrict__ outH, int N)
{
  int gw = (blockIdx.x*256 + threadIdx.x) >> 6;
  if (gw >= N) return;
  int lane = threadIdx.x & 63;
  int j0 = lane*2;
  int h0 = j0 / D;
  int beg = rowptr[gw], end = rowptr[gw+1];
  float edv = ed[gw*H + h0];
  float den = 0.f, a0 = 0.f, a1 = 0.f;
  int t = beg;
  for (; t + 4 <= end; t += 4){
    int s0 = csr[t], s1 = csr[t+1], s2 = csr[t+2], s3 = csr[t+3];
    float e0 = es[s0*H + h0] + edv; e0 = e0 > 0.f ? e0 : 0.2f*e0;
    float e1 = es[s1*H + h0] + edv; e1 = e1 > 0.f ? e1 : 0.2f*e1;
    float e2 = es[s2*H + h0] + edv; e2 = e2 > 0.f ? e2 : 0.2f*e2;
    float e3 = es[s3*H + h0] + edv; e3 = e3 > 0.f ? e3 : 0.2f*e3;
    __half2 q0 = *(const __half2*)(xp + (size_t)s0*128 + j0);
    __half2 q1 = *(const __half2*)(xp + (size_t)s1*128 + j0);
    __half2 q2 = *(const __half2*)(xp + (size_t)s2*128 + j0);
    __half2 q3 = *(const __half2*)(xp + (size_t)s3*128 + j0);
    float w0 = __expf(e0), w1 = __expf(e1), w2 = __expf(e2), w3 = __expf(e3);
    float2 f0 = __half22float2(q0), f1 = __half22float2(q1);
    float2 f2 = __half22float2(q2), f3 = __half22float2(q3);
    den += (w0 + w1) + (w2 + w3);
    a0  += w0*f0.x + w1*f1.x + w2*f2.x + w3*f3.x;
    a1  += w0*f0.y + w1*f1.y + w2*f2.y + w3*f3.y;
  }
  for (; t < end; t++){
    int s = csr[t];
    float e = es[s*H + h0] + edv;
    e = e > 0.f ? e : 0.2f*e;
    float w = __expf(e);
    float2 f = __half22float2(*(const __half2*)(xp + (size_t)s*128 + j0));
    den += w;
    a0  += w*f.x;
    a1  += w*f.y;
  }
  float inv = 1.f / den;
  float o0 = a0*inv + bg[j0];
  float o1 = a1*inv + bg[j0+1];
  o0 = o0 > 0.f ? o0 : __expf(o0) - 1.f;
  o1 = o1 > 0.f ? o1 : __expf(o1) - 1.f;
  if (res){ o0 += res[(size_t)gw*128 + j0]; o1 += res[(size_t)gw*128 + j0 + 1]; }
  *(float2*)(out + (size_t)gw*128 + j0) = make_float2(o0, o1);
  *(__half2*)(outH + (size_t)gw*128 + j0) = __floats2half2_rn(o0, o1);
}

// ---------------- pooling --------------------------------------------------------
__global__ __launch_bounds__(128) void k_pool(const float* __restrict__ enh,
    const int* __restrict__ batch, float* __restrict__ Ps, float* __restrict__ Pss,
    unsigned* __restrict__ Pmx, float* __restrict__ Pcnt, int N)
{
  int tid = threadIdx.x;
  int n0 = blockIdx.x * 128;
  if (n0 >= N) return;
  int n1 = min(n0 + 128, N);
  int cur = batch[n0];
  float sum = 0.f, ssq = 0.f, mx = -1e30f, cnt = 0.f;
  auto flush = [&](int b){
    atomicAdd(&Ps[b*128 + tid], sum);
    atomicAdd(&Pss[b*128 + tid], ssq);
    atomicMax(&Pmx[b*128 + tid], f2mono(mx));
    if (tid == 0) atomicAdd(&Pcnt[b], cnt);
  };
  for (int i = n0; i < n1; i++){
    int b = batch[i];
    if (b != cur){ flush(cur); cur = b; sum = 0.f; ssq = 0.f; mx = -1e30f; cnt = 0.f; }
    float v = enh[(size_t)i*128 + tid];
    sum += v; ssq += v*v; mx = fmaxf(mx, v); cnt += 1.f;
  }
  flush(cur);
}

// ---------------- fused poolfin + cls1 -------------------------------------------
__global__ void k_poolcls(const float* __restrict__ Ps, const float* __restrict__ Pss,
    const unsigned* __restrict__ Pmx, const float* __restrict__ Pcnt,
    const float* __restrict__ Wc1, const float* __restrict__ bc1, float* __restrict__ c1b)
{
  __shared__ float gs[384];
  int b = blockIdx.x, j = threadIdx.x;             // 64 x 128
  float cnt = Pcnt[b];
  float c = fmaxf(cnt, 1.f);
  float mean = Ps[b*128 + j] / c;
  float var = (Pss[b*128 + j] - c*mean*mean) / fmaxf(cnt - 1.f, 1.f);
  float sd = (cnt > 1.f) ? sqrtf(fmaxf(var, 0.f)) : 0.f;
  gs[j] = mean; gs[128 + j] = mono2f(Pmx[b*128 + j]); gs[256 + j] = sd;
  __syncthreads();
  float acc = bc1[j];
  for (int i = 0; i < 384; i++) acc += gs[i] * Wc1[j*384 + i];
  c1b[b*128 + j] = fmaxf(acc, 0.f);
}
// ---------------- fused cls2 + cls3 ----------------------------------------------
__global__ void k_cls23(const float* __restrict__ c1b, const float* __restrict__ Wc2,
    const float* __restrict__ bc2, const float* __restrict__ Wc3,
    const float* __restrict__ bc3, float* __restrict__ out)
{
  __shared__ float hs[128];
  __shared__ float h2[64];
  int b = blockIdx.x, t = threadIdx.x;             // 64 x 64
  hs[t] = c1b[b*128 + t]; hs[t + 64] = c1b[b*128 + t + 64];
  __syncthreads();
  float acc = bc2[t];
  for (int i = 0; i < 128; i++) acc += hs[i] * Wc2[t*128 + i];
  h2[t] = fmaxf(acc, 0.f);
  __syncthreads();
  if (t < 2){
    float a = bc3[t];
    for (int i = 0; i < 64; i++) a += h2[i] * Wc3[t*64 + i];
    out[b*2 + t] = a;
  }
}

// ---------------- launch ---------------------------------------------------------
extern "C" void kernel_launch(void* const* d_in, const int* in_sizes, int n_in,
                              void* d_out, int out_size, void* d_ws, size_t ws_size,
                              hipStream_t stream)
{
  const float* x    = (const float*)d_in[0];
  const int*  ei    = (const int*)d_in[1];
  const int*  batch = (const int*)d_in[2];
  const float* Wi1  = (const float*)d_in[3];  const float* bi1 = (const float*)d_in[4];
  const float* Wi2  = (const float*)d_in[5];  const float* bi2 = (const float*)d_in[6];
  const float* Wg[4]= {(const float*)d_in[7],(const float*)d_in[11],(const float*)d_in[15],(const float*)d_in[19]};
  const float* As[4]= {(const float*)d_in[8],(const float*)d_in[12],(const float*)d_in[16],(const float*)d_in[20]};
  const float* Ad[4]= {(const float*)d_in[9],(const float*)d_in[13],(const float*)d_in[17],(const float*)d_in[21]};
  const float* bg[4]= {(const float*)d_in[10],(const float*)d_in[14],(const float*)d_in[18],(const float*)d_in[22]};
  const float* We1  = (const float*)d_in[23]; const float* be1 = (const float*)d_in[24];
  const float* We2  = (const float*)d_in[25]; const float* be2 = (const float*)d_in[26];
  const float* Wc1  = (const float*)d_in[27]; const float* bc1 = (const float*)d_in[28];
  const float* Wc2  = (const float*)d_in[29]; const float* bc2 = (const float*)d_in[30];
  const float* Wc3  = (const float*)d_in[31]; const float* bc3 = (const float*)d_in[32];
  float* outp = (float*)d_out;

  const int N = in_sizes[2];
  const int E = in_sizes[1] / 2;
  const int Etot = E + N;

  float* base = (float*)d_ws;
  size_t off = 0;
  auto alloc = [&](size_t elems) -> float* {
    float* p = base + off;
    off += (elems + 3) & ~(size_t)3;
    return p;
  };
  float* A    = alloc((size_t)N * 128);          // f32 residual stream / enh
  __half* Bh  = (__half*)alloc((size_t)N * 64);  // f16 gemm scratch
  __half* Xh  = (__half*)alloc((size_t)N * 64);  // f16 xp (also cast-of-x)
  __half* Ah  = (__half*)alloc((size_t)N * 64);  // f16 shadow of A
  f16* Wh     = (f16*)alloc(8 * 8192);           // 8 x 128x128 f16 weights
  float* es   = alloc((size_t)N * 8);
  float* ed   = alloc((size_t)N * 8);
  float* Ps   = alloc(64 * 128);                 // Ps..fil contiguous -> ONE memset
  float* Pss  = alloc(64 * 128);
  unsigned* Pmx = (unsigned*)alloc(64 * 128);
  float* Pcnt = alloc(64);
  int* deg    = (int*)alloc(N);
  int* fil    = (int*)alloc(N);
  int* rowptr = (int*)alloc(N + 1);
  int* bsum   = (int*)alloc(512);
  int* boff   = (int*)alloc(512);
  int* csr    = (int*)alloc(Etot);
  float* c1b  = alloc(64 * 128);
  (void)ws_size; (void)n_in; (void)out_size;

  (void)hipMemsetAsync(Ps, 0, sizeof(float) * (3*8192 + 64) + sizeof(int) * 2 * (size_t)N, stream);

  WPtrs wp;
  wp.w[0]=Wi1; wp.w[1]=Wi2; wp.w[2]=Wg[0]; wp.w[3]=Wg[1]; wp.w[4]=Wg[2]; wp.w[5]=Wg[3]; wp.w[6]=We1; wp.w[7]=We2;
  k_wcast<<<dim3(8, 8), 256, 0, stream>>>(wp, Wh);
  k_castx<<<(N*128/8 + 255) / 256, 256, 0, stream>>>(x, Xh, N*128);

  const int gtiles = 2 * ((N + 31) / 32);        // col-split x2
  k_gemm_f16<1><<<gtiles, 256, 0, stream>>>(Xh, Wh + 0*16384, bi1, nullptr, nullptr, Bh, N);
  k_gemm_f16<0><<<gtiles, 256, 0, stream>>>(Bh, Wh + 1*16384, bi2, nullptr, A, Ah, N);

  const int nb = (N + 255) / 256;
  k_deg  <<<(Etot + 255) / 256, 256, 0, stream>>>(ei, deg, E, N);
  k_scan1<<<nb, 256, 0, stream>>>(deg, bsum, N);
  k_scan2<<<1, 256, 0, stream>>>(bsum, boff, nb);
  k_scan3<<<nb, 256, 0, stream>>>(deg, boff, rowptr, N);
  k_fill <<<(Etot + 255) / 256, 256, 0, stream>>>(ei, rowptr, fil, csr, E, N);

  for (int l = 0; l < 4; l++){
    k_gemm_f16<0><<<gtiles, 256, 0, stream>>>(Ah, Wh + (size_t)(2+l)*16384, nullptr, nullptr, nullptr, Xh, N);
    if (l < 3){
      k_prep8<<<(N*8 + 255) / 256, 256, 0, stream>>>(Xh, As[l], Ad[l], es, ed, N);
      k_aggregate<8,16><<<(N + 3) / 4, 256, 0, stream>>>(Xh, es, ed, rowptr, csr, bg[l],
                                                         l > 0 ? A : nullptr, A, Ah, N);
    } else {
      k_prep1<<<(N + 3) / 4, 256, 0, stream>>>(Xh, As[3], Ad[3], es, ed, N);
      k_aggregate<1,128><<<(N + 3) / 4, 256, 0, stream>>>(Xh, es, ed, rowptr, csr, bg[3], A, A, Ah, N);
    }
  }

  // enh = A + (relu(A@We1^T+be1)@We2^T + be2), into A (f32)
  k_gemm_f16<1><<<gtiles, 256, 0, stream>>>(Ah, Wh + 6*16384, be1, nullptr, nullptr, Bh, N);
  k_gemm_f16<0><<<gtiles, 256, 0, stream>>>(Bh, Wh + 7*16384, be2, A, A, nullptr, N);

  k_pool   <<<(N + 127) / 128, 128, 0, stream>>>(A, batch, Ps, Pss, Pmx, Pcnt, N);
  k_poolcls<<<64, 128, 0, stream>>>(Ps, Pss, Pmx, Pcnt, Wc1, bc1, c1b);
  k_cls23  <<<64, 64, 0, stream>>>(c1b, Wc2, bc2, Wc3, bc3, outp);
}

// Round 11
// 604.652 us; speedup vs baseline: 1.1465x; 1.0559x over previous
//
#include <hip/hip_runtime.h>
#include <hip/hip_fp16.h>
#include <cstddef>

typedef _Float16 f16;
typedef f16 f16x8 __attribute__((ext_vector_type(8)));
typedef float f32x4 __attribute__((ext_vector_type(4)));

__device__ __forceinline__ unsigned f2mono(float f){
  unsigned u = __float_as_uint(f);
  return (u & 0x80000000u) ? ~u : (u | 0x80000000u);
}
__device__ __forceinline__ float mono2f(unsigned u){
  return (u & 0x80000000u) ? __uint_as_float(u & 0x7fffffffu) : __uint_as_float(~u);
}

// ---------------- weight cast f32 -> f16, 8 x 128x128 ---------------------------
struct WPtrs { const float* w[8]; };
__global__ void k_wcast(WPtrs p, f16* __restrict__ Wh){
  int wi = blockIdx.y;
  const float* W = p.w[wi];
  f16* dst = Wh + (size_t)wi * 16384;
  int i = (blockIdx.x*256 + threadIdx.x) * 8;
  float4 v0 = *(const float4*)(W + i), v1 = *(const float4*)(W + i + 4);
  f16x8 h = {(f16)v0.x,(f16)v0.y,(f16)v0.z,(f16)v0.w,
             (f16)v1.x,(f16)v1.y,(f16)v1.z,(f16)v1.w};
  *(f16x8*)(dst + i) = h;
}

// ---------------- MFMA f16 GEMM: 32 rows x 64 cols per block ---------------------
// grid = 2*ceil(n/32); blockIdx&1 = col half. LDS ~24.4 KB -> 6 blocks/CU.
// out[r][j] = act(sum_k in[r][k]*W[j][k] + b[j]) (+res). TIN = __half or float.
template<int ACT, typename TIN>   // 0 none, 1 relu
__global__ __launch_bounds__(256) void k_gemm_f16(
    const TIN* __restrict__ in, const f16* __restrict__ Wm,
    const float* __restrict__ bias, const float* __restrict__ res,
    float* __restrict__ outF, __half* __restrict__ outH, int n)
{
  constexpr int LDW = 130;
  __shared__ f16 Wl[64*LDW];
  __shared__ f16 Al[32*LDW];
  const int tid = threadIdx.x;
  const int ch = blockIdx.x & 1;
  const int r0 = (blockIdx.x >> 1) * 32;
#pragma unroll
  for (int i = 0; i < 4; i++){
    int u = tid + 256*i; int row = u >> 4, c8 = (u & 15) * 8;
    *(f16x8*)&Wl[row*LDW + c8] = *(const f16x8*)(Wm + (size_t)(ch*64 + row)*128 + c8);
  }
#pragma unroll
  for (int i = 0; i < 2; i++){
    int u = tid + 256*i; int row = u >> 4, c8 = (u & 15) * 8;
    int gr = r0 + row;
    f16x8 v = {};
    if (gr < n){
      if constexpr (__is_same(TIN, __half)){
        v = *(const f16x8*)((const f16*)in + (size_t)gr*128 + c8);
      } else {
        const float4* q = (const float4*)((const float*)in + (size_t)gr*128 + c8);
        float4 v0 = q[0], v1 = q[1];
        v = f16x8{(f16)v0.x,(f16)v0.y,(f16)v0.z,(f16)v0.w,
                  (f16)v1.x,(f16)v1.y,(f16)v1.z,(f16)v1.w};
      }
    }
    *(f16x8*)&Al[row*LDW + c8] = v;
  }
  __syncthreads();
  const int wv = tid >> 6, lane = tid & 63;
  const int l15 = lane & 15, quad = lane >> 4;
  const int rh = wv & 1, cq = wv >> 1;
  f32x4 acc[2] = {};
  const f16* Ab = &Al[(rh*16 + l15)*LDW + quad*8];
  const f16* Bb = &Wl[(cq*32 + l15)*LDW + quad*8];
#pragma unroll
  for (int kc = 0; kc < 4; kc++){
    f16x8 a = *(const f16x8*)(Ab + kc*32);
#pragma unroll
    for (int nt = 0; nt < 2; nt++){
      f16x8 b = *(const f16x8*)(Bb + nt*16*LDW + kc*32);
      acc[nt] = __builtin_amdgcn_mfma_f32_16x16x32_f16(a, b, acc[nt], 0, 0, 0);
    }
  }
#pragma unroll
  for (int nt = 0; nt < 2; nt++){
    int col = ch*64 + cq*32 + nt*16 + l15;
    float bv = bias ? bias[col] : 0.f;
#pragma unroll
    for (int reg = 0; reg < 4; reg++){
      int gr = r0 + rh*16 + quad*4 + reg;
      if (gr >= n) continue;
      float o = acc[nt][reg] + bv;
      if (ACT == 1) o = fmaxf(o, 0.f);
      if (res) o += res[(size_t)gr*128 + col];
      if (outF) outF[(size_t)gr*128 + col] = o;
      if (outH) outH[(size_t)gr*128 + col] = __float2half(o);
    }
  }
}

// ---------------- attention logits prep (xp in fp16) ---------------------------
__global__ void k_prep8(const __half* __restrict__ xp, const float* __restrict__ As,
                        const float* __restrict__ Ad, float* __restrict__ es,
                        float* __restrict__ ed, int N){
  int t = blockIdx.x*blockDim.x + threadIdx.x;
  if (t >= N*8) return;
  int node = t >> 3, h = t & 7;
  const __half2* xr = (const __half2*)(xp + (size_t)node*128 + h*16);
  float ss = 0.f, sd = 0.f;
#pragma unroll
  for (int w = 0; w < 8; w++){
    float2 v = __half22float2(xr[w]);
    int i = h*16 + w*2;
    ss += v.x*As[i] + v.y*As[i+1];
    sd += v.x*Ad[i] + v.y*Ad[i+1];
  }
  es[t] = ss; ed[t] = sd;
}
__global__ __launch_bounds__(256) void k_prep1(const __half* __restrict__ xp,
    const float* __restrict__ As, const float* __restrict__ Ad,
    float* __restrict__ es, float* __restrict__ ed, int N){
  int gw = (blockIdx.x*256 + threadIdx.x) >> 6;
  if (gw >= N) return;
  int lane = threadIdx.x & 63;
  float2 x = __half22float2(*(const __half2*)(xp + (size_t)gw*128 + lane*2));
  float s = x.x*As[lane*2] + x.y*As[lane*2+1];
  float d = x.x*Ad[lane*2] + x.y*Ad[lane*2+1];
#pragma unroll
  for (int o = 32; o > 0; o >>= 1){ s += __shfl_down(s, o); d += __shfl_down(d, o); }
  if (lane == 0){ es[gw] = s; ed[gw] = d; }
}

// ---------------- CSR build -----------------------------------------------------
__global__ void k_deg(const int* __restrict__ ei, int* __restrict__ deg, int E, int N){
  int t = blockIdx.x*blockDim.x + threadIdx.x;
  if (t >= E + N) return;
  int d = (t < E) ? ei[E + t] : (t - E);
  atomicAdd(&deg[d], 1);
}
__global__ void k_scan1(const int* __restrict__ deg, int* __restrict__ bsum, int N){
  __shared__ int sd[256];
  int i = blockIdx.x*256 + threadIdx.x;
  sd[threadIdx.x] = (i < N) ? deg[i] : 0;
  __syncthreads();
  for (int s = 128; s > 0; s >>= 1){
    if (threadIdx.x < s) sd[threadIdx.x] += sd[threadIdx.x + s];
    __syncthreads();
  }
  if (threadIdx.x == 0) bsum[blockIdx.x] = sd[0];
}
__global__ void k_scan2(const int* __restrict__ bsum, int* __restrict__ boff, int nb){
  __shared__ int sd[256];
  int t = threadIdx.x;
  int v = (t < nb) ? bsum[t] : 0;
  sd[t] = v;
  __syncthreads();
  for (int s = 1; s < 256; s <<= 1){
    int u = (t >= s) ? sd[t - s] : 0;
    __syncthreads();
    sd[t] += u;
    __syncthreads();
  }
  if (t < nb) boff[t] = sd[t] - v;
}
__global__ void k_scan3(const int* __restrict__ deg, const int* __restrict__ boff,
                        int* __restrict__ rowptr, int N){
  __shared__ int sd[256];
  int tid = threadIdx.x;
  int i = blockIdx.x*256 + tid;
  sd[tid] = (i < N) ? deg[i] : 0;
  __syncthreads();
  for (int s = 1; s < 256; s <<= 1){
    int t = (tid >= s) ? sd[tid - s] : 0;
    __syncthreads();
    sd[tid] += t;
    __syncthreads();
  }
  if (i < N) rowptr[i+1] = boff[blockIdx.x] + sd[tid];
  if (i == 0) rowptr[0] = 0;
}
__global__ void k_fill(const int* __restrict__ ei, const int* __restrict__ rowptr,
                       int* __restrict__ fil, int* __restrict__ csr, int E, int N){
  int t = blockIdx.x*blockDim.x + threadIdx.x;
  if (t >= E + N) return;
  int s, d;
  if (t < E){ s = ei[t]; d = ei[E + t]; } else { s = d = t - E; }
  int pos = rowptr[d] + atomicAdd(&fil[d], 1);
  csr[pos] = s;
}

// ---------------- GAT aggregate v3: cooperative logits + 8-deep gathers ---------
// one wave per dst node. Per 8-edge batch: lane = head*8 + edge computes ONE
// logit+exp (vs 8 redundant before), weights/srcs broadcast by shuffle.
template<int H, int D>
__global__ __launch_bounds__(256) void k_aggregate(
    const __half* __restrict__ xp, const float* __restrict__ es, const float* __restrict__ ed,
    const int* __restrict__ rowptr, const int* __restrict__ csr,
    const float* __restrict__ bg, const float* res,
    float* out, __half* __restrict__ outH, int N)
{
  int gw = (blockIdx.x*256 + threadIdx.x) >> 6;
  if (gw >= N) return;
  const int lane = threadIdx.x & 63;
  const int j0 = lane*2;
  const int h0 = (H == 8) ? (lane >> 3) : 0;       // own head == pair head
  const int k8 = lane & 7;
  int beg = rowptr[gw], end = rowptr[gw+1];
  float edv = ed[gw*H + h0];
  float den = 0.f, a0 = 0.f, a1 = 0.f;
  for (int t = beg; t < end; t += 8){
    int nb = end - t; if (nb > 8) nb = 8;
    int idx = t + (k8 < nb ? k8 : nb - 1);
    int sE = csr[idx];
    float e = es[sE*H + h0] + edv;
    e = e > 0.f ? e : 0.2f*e;
    if (k8 >= nb) e = -1e30f;                      // tail: zero weight
    float w = __expf(e);
#pragma unroll
    for (int k = 0; k < 8; k++){
      float wk = __shfl(w, (h0 << 3) + k);
      int   sk = __shfl(sE, k);
      float2 f = __half22float2(*(const __half2*)(xp + (size_t)sk*128 + j0));
      den += wk; a0 += wk*f.x; a1 += wk*f.y;
    }
  }
  float inv = 1.f / den;
  float o0 = a0*inv + bg[j0];
  float o1 = a1*inv + bg[j0+1];
  o0 = o0 > 0.f ? o0 : __expf(o0) - 1.f;
  o1 = o1 > 0.f ? o1 : __expf(o1) - 1.f;
  if (res){ o0 += res[(size_t)gw*128 + j0]; o1 += res[(size_t)gw*128 + j0 + 1]; }
  *(float2*)(out + (size_t)gw*128 + j0) = make_float2(o0, o1);
  *(__half2*)(outH + (size_t)gw*128 + j0) = __floats2half2_rn(o0, o1);
}

// ---------------- pooling --------------------------------------------------------
__global__ __launch_bounds__(128) void k_pool(const float* __restrict__ enh,
    const int* __restrict__ batch, float* __restrict__ Ps, float* __restrict__ Pss,
    unsigned* __restrict__ Pmx, float* __restrict__ Pcnt, int N)
{
  int tid = threadIdx.x;
  int n0 = blockIdx.x * 128;
  if (n0 >= N) return;
  int n1 = min(n0 + 128, N);
  int cur = batch[n0];
  float sum = 0.f, ssq = 0.f, mx = -1e30f, cnt = 0.f;
  auto flush = [&](int b){
    atomicAdd(&Ps[b*128 + tid], sum);
    atomicAdd(&Pss[b*128 + tid], ssq);
    atomicMax(&Pmx[b*128 + tid], f2mono(mx));
    if (tid == 0) atomicAdd(&Pcnt[b], cnt);
  };
  for (int i = n0; i < n1; i++){
    int b = batch[i];
    if (b != cur){ flush(cur); cur = b; sum = 0.f; ssq = 0.f; mx = -1e30f; cnt = 0.f; }
    float v = enh[(size_t)i*128 + tid];
    sum += v; ssq += v*v; mx = fmaxf(mx, v); cnt += 1.f;
  }
  flush(cur);
}

// ---------------- fused poolfin + cls1 -------------------------------------------
__global__ void k_poolcls(const float* __restrict__ Ps, const float* __restrict__ Pss,
    const unsigned* __restrict__ Pmx, const float* __restrict__ Pcnt,
    const float* __restrict__ Wc1, const float* __restrict__ bc1, float* __restrict__ c1b)
{
  __shared__ float gs[384];
  int b = blockIdx.x, j = threadIdx.x;
  float cnt = Pcnt[b];
  float c = fmaxf(cnt, 1.f);
  float mean = Ps[b*128 + j] / c;
  float var = (Pss[b*128 + j] - c*mean*mean) / fmaxf(cnt - 1.f, 1.f);
  float sd = (cnt > 1.f) ? sqrtf(fmaxf(var, 0.f)) : 0.f;
  gs[j] = mean; gs[128 + j] = mono2f(Pmx[b*128 + j]); gs[256 + j] = sd;
  __syncthreads();
  float acc = bc1[j];
  for (int i = 0; i < 384; i++) acc += gs[i] * Wc1[j*384 + i];
  c1b[b*128 + j] = fmaxf(acc, 0.f);
}
// ---------------- fused cls2 + cls3 ----------------------------------------------
__global__ void k_cls23(const float* __restrict__ c1b, const float* __restrict__ Wc2,
    const float* __restrict__ bc2, const float* __restrict__ Wc3,
    const float* __restrict__ bc3, float* __restrict__ out)
{
  __shared__ float hs[128];
  __shared__ float h2[64];
  int b = blockIdx.x, t = threadIdx.x;
  hs[t] = c1b[b*128 + t]; hs[t + 64] = c1b[b*128 + t + 64];
  __syncthreads();
  float acc = bc2[t];
  for (int i = 0; i < 128; i++) acc += hs[i] * Wc2[t*128 + i];
  h2[t] = fmaxf(acc, 0.f);
  __syncthreads();
  if (t < 2){
    float a = bc3[t];
    for (int i = 0; i < 64; i++) a += h2[i] * Wc3[t*64 + i];
    out[b*2 + t] = a;
  }
}

// ---------------- launch ---------------------------------------------------------
extern "C" void kernel_launch(void* const* d_in, const int* in_sizes, int n_in,
                              void* d_out, int out_size, void* d_ws, size_t ws_size,
                              hipStream_t stream)
{
  const float* x    = (const float*)d_in[0];
  const int*  ei    = (const int*)d_in[1];
  const int*  batch = (const int*)d_in[2];
  const float* Wi1  = (const float*)d_in[3];  const float* bi1 = (const float*)d_in[4];
  const float* Wi2  = (const float*)d_in[5];  const float* bi2 = (const float*)d_in[6];
  const float* Wg[4]= {(const float*)d_in[7],(const float*)d_in[11],(const float*)d_in[15],(const float*)d_in[19]};
  const float* As[4]= {(const float*)d_in[8],(const float*)d_in[12],(const float*)d_in[16],(const float*)d_in[20]};
  const float* Ad[4]= {(const float*)d_in[9],(const float*)d_in[13],(const float*)d_in[17],(const float*)d_in[21]};
  const float* bg[4]= {(const float*)d_in[10],(const float*)d_in[14],(const float*)d_in[18],(const float*)d_in[22]};
  const float* We1  = (const float*)d_in[23]; const float* be1 = (const float*)d_in[24];
  const float* We2  = (const float*)d_in[25]; const float* be2 = (const float*)d_in[26];
  const float* Wc1  = (const float*)d_in[27]; const float* bc1 = (const float*)d_in[28];
  const float* Wc2  = (const float*)d_in[29]; const float* bc2 = (const float*)d_in[30];
  const float* Wc3  = (const float*)d_in[31]; const float* bc3 = (const float*)d_in[32];
  float* outp = (float*)d_out;

  const int N = in_sizes[2];
  const int E = in_sizes[1] / 2;
  const int Etot = E + N;

  float* base = (float*)d_ws;
  size_t off = 0;
  auto alloc = [&](size_t elems) -> float* {
    float* p = base + off;
    off += (elems + 3) & ~(size_t)3;
    return p;
  };
  float* A    = alloc((size_t)N * 128);
  __half* Bh  = (__half*)alloc((size_t)N * 64);
  __half* Xh  = (__half*)alloc((size_t)N * 64);
  __half* Ah  = (__half*)alloc((size_t)N * 64);
  f16* Wh     = (f16*)alloc(8 * 8192);
  float* es   = alloc((size_t)N * 8);
  float* ed   = alloc((size_t)N * 8);
  float* Ps   = alloc(64 * 128);                 // Ps..fil contiguous -> ONE memset
  float* Pss  = alloc(64 * 128);
  unsigned* Pmx = (unsigned*)alloc(64 * 128);
  float* Pcnt = alloc(64);
  int* deg    = (int*)alloc(N);
  int* fil    = (int*)alloc(N);
  int* rowptr = (int*)alloc(N + 1);
  int* bsum   = (int*)alloc(512);
  int* boff   = (int*)alloc(512);
  int* csr    = (int*)alloc(Etot);
  float* c1b  = alloc(64 * 128);
  (void)ws_size; (void)n_in; (void)out_size;

  (void)hipMemsetAsync(Ps, 0, sizeof(float) * (3*8192 + 64) + sizeof(int) * 2 * (size_t)N, stream);

  WPtrs wp;
  wp.w[0]=Wi1; wp.w[1]=Wi2; wp.w[2]=Wg[0]; wp.w[3]=Wg[1]; wp.w[4]=Wg[2]; wp.w[5]=Wg[3]; wp.w[6]=We1; wp.w[7]=We2;
  k_wcast<<<dim3(8, 8), 256, 0, stream>>>(wp, Wh);

  const int gtiles = 2 * ((N + 31) / 32);
  k_gemm_f16<1, float ><<<gtiles, 256, 0, stream>>>(x,  Wh + 0*16384, bi1, nullptr, nullptr, Bh, N);
  k_gemm_f16<0, __half><<<gtiles, 256, 0, stream>>>(Bh, Wh + 1*16384, bi2, nullptr, A, Ah, N);

  const int nb = (N + 255) / 256;
  k_deg  <<<(Etot + 255) / 256, 256, 0, stream>>>(ei, deg, E, N);
  k_scan1<<<nb, 256, 0, stream>>>(deg, bsum, N);
  k_scan2<<<1, 256, 0, stream>>>(bsum, boff, nb);
  k_scan3<<<nb, 256, 0, stream>>>(deg, boff, rowptr, N);
  k_fill <<<(Etot + 255) / 256, 256, 0, stream>>>(ei, rowptr, fil, csr, E, N);

  for (int l = 0; l < 4; l++){
    k_gemm_f16<0, __half><<<gtiles, 256, 0, stream>>>(Ah, Wh + (size_t)(2+l)*16384, nullptr, nullptr, nullptr, Xh, N);
    if (l < 3){
      k_prep8<<<(N*8 + 255) / 256, 256, 0, stream>>>(Xh, As[l], Ad[l], es, ed, N);
      k_aggregate<8,16><<<(N + 3) / 4, 256, 0, stream>>>(Xh, es, ed, rowptr, csr, bg[l],
                                                         l > 0 ? A : nullptr, A, Ah, N);
    } else {
      k_prep1<<<(N + 3) / 4, 256, 0, stream>>>(Xh, As[3], Ad[3], es, ed, N);
      k_aggregate<1,128><<<(N + 3) / 4, 256, 0, stream>>>(Xh, es, ed, rowptr, csr, bg[3], A, A, Ah, N);
    }
  }

  // enh = A + (relu(A@We1^T+be1)@We2^T + be2), into A (f32)
  k_gemm_f16<1, __half><<<gtiles, 256, 0, stream>>>(Ah, Wh + 6*16384, be1, nullptr, nullptr, Bh, N);
  k_gemm_f16<0, __half><<<gtiles, 256, 0, stream>>>(Bh, Wh + 7*16384, be2, A, A, nullptr, N);

  k_pool   <<<(N + 127) / 128, 128, 0, stream>>>(A, batch, Ps, Pss, Pmx, Pcnt, N);
  k_poolcls<<<64, 128, 0, stream>>>(Ps, Pss, Pmx, Pcnt, Wc1, bc1, c1b);
  k_cls23  <<<64, 64, 0, stream>>>(c1b, Wc2, bc2, Wc3, bc3, outp);
}